// Round 1
// baseline (123.763 us; speedup 1.0000x reference)
//
#include <hip/hip_runtime.h>
#include <hip/hip_bf16.h>

// BoundaryLoss: out = mean(|softmax(pred,axis=1) * (posEDT - negEDT)|)
// B=2, C=4, D=H=W=48. Workspace: 16 fp32 volumes of 48^3 (2 masks * B * C).
// EDT is exact separable squared-distance min-plus; all intermediates are exact
// integers (<=6627) or fp32(1e9), so results match the JAX reference bit-exactly.

#define SPATIAL 110592   // 48^3
#define NB 2
#define NC 4
#define NLINE 48

__global__ void init_kernel(const int* __restrict__ target, float* __restrict__ F) {
    int i = blockIdx.x * 256 + threadIdx.x;       // over B*SPATIAL
    if (i >= NB * SPATIAL) return;
    int b = i / SPATIAL, s = i - b * SPATIAL;
    int t = target[i];
#pragma unroll
    for (int c = 0; c < NC; ++c) {
        bool pos = (t == c);
        F[(long)(b * NC + c) * SPATIAL + s]            = pos ? 0.0f : 1e9f;  // pos mask
        F[(long)(NB * NC + b * NC + c) * SPATIAL + s]  = pos ? 1e9f : 0.0f;  // neg mask
    }
}

// One block handles a 48x48 slab: transform axis j (stride sJ), column axis c
// (stride sC), slab axis a (stride sA). jInner selects which of j/c is the
// fast thread index so that global loads/stores are coalesced (inner = the
// axis with stride 1). LDS row padded to 49 to avoid bank conflicts.
__global__ void edt_pass(float* __restrict__ F, int sJ, int sC, int sA, int jInner) {
    __shared__ float lds[NLINE * 49];
    int blk = blockIdx.x;                  // v*48 + a, v in [0,16)
    int v = blk / NLINE, a = blk - v * NLINE;
    long base = (long)v * SPATIAL + (long)a * sA;
    int tid = threadIdx.x;                 // 256 threads

    for (int idx = tid; idx < NLINE * NLINE; idx += 256) {
        int p = idx & 47, q = idx / NLINE;   // NLINE=48 -> idx%48 != idx&47! fix below
        p = idx % NLINE; // (48 is not a power of two)
        int j = jInner ? p : q;
        int c = jInner ? q : p;
        lds[j * 49 + c] = F[base + (long)j * sJ + (long)c * sC];
    }
    __syncthreads();
    for (int idx = tid; idx < NLINE * NLINE; idx += 256) {
        int p = idx % NLINE, q = idx / NLINE;
        int x = jInner ? p : q;
        int c = jInner ? q : p;
        float m = 1e30f;
#pragma unroll
        for (int j = 0; j < NLINE; ++j) {
            int dx = x - j;
            m = fminf(m, lds[j * 49 + c] + (float)(dx * dx));
        }
        F[base + (long)x * sJ + (long)c * sC] = m;
    }
}

__global__ void final_kernel(const float* __restrict__ pred, const float* __restrict__ F,
                             float* __restrict__ out) {
    int i = blockIdx.x * 256 + threadIdx.x;     // over B*SPATIAL
    float contrib = 0.0f;
    if (i < NB * SPATIAL) {
        int b = i / SPATIAL, s = i - b * SPATIAL;
        float p[NC];
        float mx = -1e30f;
#pragma unroll
        for (int c = 0; c < NC; ++c) {
            p[c] = pred[(long)(b * NC + c) * SPATIAL + s];
            mx = fmaxf(mx, p[c]);
        }
        float sum = 0.0f;
#pragma unroll
        for (int c = 0; c < NC; ++c) { p[c] = expf(p[c] - mx); sum += p[c]; }
        float inv = 1.0f / sum;
#pragma unroll
        for (int c = 0; c < NC; ++c) {
            float psq = F[(long)(b * NC + c) * SPATIAL + s];
            float nsq = F[(long)(NB * NC + b * NC + c) * SPATIAL + s];
            // class absent in this batch element <=> psq == 1e9 uniformly
            float sdf = (psq > 1e8f) ? 0.0f : (sqrtf(psq) - sqrtf(nsq));
            contrib += p[c] * inv * fabsf(sdf);
        }
    }
    // block reduction: wave64 shuffle, then cross-wave via LDS
    float v = contrib;
#pragma unroll
    for (int o = 32; o > 0; o >>= 1) v += __shfl_down(v, o, 64);
    __shared__ float wsum[4];
    int lane = threadIdx.x & 63, wid = threadIdx.x >> 6;
    if (lane == 0) wsum[wid] = v;
    __syncthreads();
    if (wid == 0) {
        v = (lane < 4) ? wsum[lane] : 0.0f;
        v += __shfl_down(v, 2, 64);
        v += __shfl_down(v, 1, 64);
        if (lane == 0) atomicAdd(out, v * (1.0f / (float)(NB * NC * SPATIAL)));
    }
}

extern "C" void kernel_launch(void* const* d_in, const int* in_sizes, int n_in,
                              void* d_out, int out_size, void* d_ws, size_t ws_size,
                              hipStream_t stream) {
    const float* pred = (const float*)d_in[0];
    const int* target = (const int*)d_in[1];
    float* out = (float*)d_out;
    float* F = (float*)d_ws;   // 16 * 110592 floats = 7.08 MB

    hipMemsetAsync(out, 0, sizeof(float), stream);

    int nvox = NB * SPATIAL;
    init_kernel<<<(nvox + 255) / 256, 256, 0, stream>>>(target, F);

    int slabs = 2 * NB * NC * NLINE;  // 16 volumes * 48 slabs = 768
    // volume layout [d][h][w]: strides d=2304, h=48, w=1
    // W-pass: j=w(1), c=h(48), a=d(2304), j is contiguous -> jInner=1
    edt_pass<<<slabs, 256, 0, stream>>>(F, 1, 48, 2304, 1);
    // H-pass: j=h(48), c=w(1), a=d(2304) -> jInner=0
    edt_pass<<<slabs, 256, 0, stream>>>(F, 48, 1, 2304, 0);
    // D-pass: j=d(2304), c=w(1), a=h(48) -> jInner=0
    edt_pass<<<slabs, 256, 0, stream>>>(F, 2304, 1, 48, 0);

    final_kernel<<<(nvox + 255) / 256, 256, 0, stream>>>(pred, F, out);
}

// Round 2
// 101.709 us; speedup vs baseline: 1.2168x; 1.2168x over previous
//
#include <hip/hip_runtime.h>
#include <hip/hip_bf16.h>

// BoundaryLoss: out = mean(|softmax(pred,axis=1) * (posEDT - negEDT)|)
// B=2, C=4, D=H=W=48. Exact separable squared EDT; all intermediates are exact
// integers (<=6627) or >=1e9 (absent class), bit-matching the JAX reference.
//
// 2 kernels:
//  A: per (vol,d) slab: onehot init -> min-plus along w -> along h -> write F
//  B: per (b,c,h): load pos+neg (d,w) slabs -> min-plus along d (both) ->
//     sdf + softmax + |.| -> block reduce -> atomicAdd
// Min-plus is register-blocked: thread owns (column, 12 consecutive outputs):
// per j: 1 ds_read + 12 x {sub/fma/min}. 12x fewer LDS reads than naive.

#define SPATIAL 110592   // 48^3
#define NB 2
#define NC 4
#define NLINE 48
#define SLABP 49         // padded LDS row stride

__global__ __launch_bounds__(192) void edt_wh_kernel(const int* __restrict__ target,
                                                     float* __restrict__ F,
                                                     float* __restrict__ out) {
    __shared__ float slab[NLINE * SLABP];
    int blk = blockIdx.x;                 // vol*48 + d ; vol = mask*8 + b*4 + c
    int vol = blk / NLINE, d = blk - vol * NLINE;
    int mask = vol >> 3;
    int b = (vol >> 2) & 1, c = vol & 3;
    int tid = threadIdx.x;
    if (blk == 0 && tid == 0) *out = 0.0f;   // visible to kernel B (stream order)

    // onehot init for this slab
    const int* tslab = target + (b * NLINE + d) * (NLINE * NLINE);
    for (int idx = tid; idx < NLINE * NLINE; idx += 192) {
        int h = idx / NLINE, w = idx - h * NLINE;
        bool pos = (tslab[idx] == c);
        bool set = mask ? !pos : pos;
        slab[h * SLABP + w] = set ? 0.0f : 1e9f;
    }
    __syncthreads();

    // ---- transform along w: thread -> (row h = tid/4, x-chunk = (tid&3)*12)
    {
        int h = tid >> 2, cx = (tid & 3) * 12;
        float m[12];
#pragma unroll
        for (int k = 0; k < 12; ++k) m[k] = 1e30f;
        float x0 = (float)cx;
        for (int j = 0; j < NLINE; ++j) {
            float fj = slab[h * SLABP + j];
            float dj = x0 - (float)j;
#pragma unroll
            for (int k = 0; k < 12; ++k) {
                float dd = dj + (float)k;
                m[k] = fminf(m[k], fmaf(dd, dd, fj));
            }
        }
        __syncthreads();               // all reads done before in-place writes
#pragma unroll
        for (int k = 0; k < 12; ++k) slab[h * SLABP + cx + k] = m[k];
        __syncthreads();
    }

    // ---- transform along h: thread -> (column w = tid/4, x-chunk over h)
    {
        int w = tid >> 2, cx = (tid & 3) * 12;
        float m[12];
#pragma unroll
        for (int k = 0; k < 12; ++k) m[k] = 1e30f;
        float x0 = (float)cx;
        for (int j = 0; j < NLINE; ++j) {
            float fj = slab[j * SLABP + w];
            float dj = x0 - (float)j;
#pragma unroll
            for (int k = 0; k < 12; ++k) {
                float dd = dj + (float)k;
                m[k] = fminf(m[k], fmaf(dd, dd, fj));
            }
        }
        __syncthreads();
#pragma unroll
        for (int k = 0; k < 12; ++k) slab[(cx + k) * SLABP + w] = m[k];
        __syncthreads();
    }

    // store slab -> F[vol][d][h][w] (coalesced)
    float* fvol = F + (long)vol * SPATIAL + (long)d * (NLINE * NLINE);
    for (int idx = tid; idx < NLINE * NLINE; idx += 192) {
        int h = idx / NLINE, w = idx - h * NLINE;
        fvol[idx] = slab[h * SLABP + w];
    }
}

__global__ __launch_bounds__(192) void edt_d_reduce_kernel(const float* __restrict__ pred,
                                                           const float* __restrict__ F,
                                                           float* __restrict__ out) {
    __shared__ float slabP[NLINE * SLABP];
    __shared__ float slabN[NLINE * SLABP];
    int blk = blockIdx.x;                 // (b*4+c)*48 + h
    int bc = blk / NLINE, h = blk - bc * NLINE;
    int b = bc >> 2, c = bc & 3;
    int tid = threadIdx.x;

    // slab[d][w] = F[vol][d][h][w], pos vol = bc, neg vol = 8 + bc
    const float* fp = F + (long)bc * SPATIAL;
    const float* fn = F + (long)(8 + bc) * SPATIAL;
    for (int idx = tid; idx < NLINE * NLINE; idx += 192) {
        int dd = idx / NLINE, w = idx - dd * NLINE;
        long g = (long)dd * (NLINE * NLINE) + h * NLINE + w;
        slabP[dd * SLABP + w] = fp[g];
        slabN[dd * SLABP + w] = fn[g];
    }
    __syncthreads();

    // min-plus along d for both slabs: thread -> (w = tid/4, d-chunk)
    int w = tid >> 2, cx = (tid & 3) * 12;
    float mP[12], mN[12];
#pragma unroll
    for (int k = 0; k < 12; ++k) { mP[k] = 1e30f; mN[k] = 1e30f; }
    float x0 = (float)cx;
    for (int j = 0; j < NLINE; ++j) {
        float fpj = slabP[j * SLABP + w];
        float fnj = slabN[j * SLABP + w];
        float dj = x0 - (float)j;
#pragma unroll
        for (int k = 0; k < 12; ++k) {
            float dd = dj + (float)k;
            float q = dd * dd;
            mP[k] = fminf(mP[k], q + fpj);
            mN[k] = fminf(mN[k], q + fnj);
        }
    }

    // contribution: |softmax_c(pred) * sdf|
    float acc = 0.0f;
    long pbase = (long)b * NC * SPATIAL + (long)h * NLINE + w;
#pragma unroll 4
    for (int k = 0; k < 12; ++k) {
        int d = cx + k;
        float psq = mP[k], nsq = mN[k];
        float sdf = (psq > 1e8f) ? 0.0f : (sqrtf(psq) - sqrtf(nsq));
        long base = pbase + (long)d * (NLINE * NLINE);
        float p0 = pred[base];
        float p1 = pred[base + SPATIAL];
        float p2 = pred[base + 2 * SPATIAL];
        float p3 = pred[base + 3 * SPATIAL];
        float mx = fmaxf(fmaxf(p0, p1), fmaxf(p2, p3));
        float e0 = __expf(p0 - mx), e1 = __expf(p1 - mx);
        float e2 = __expf(p2 - mx), e3 = __expf(p3 - mx);
        float sum = e0 + e1 + e2 + e3;
        float ec = (c == 0) ? e0 : (c == 1) ? e1 : (c == 2) ? e2 : e3;
        acc += (ec / sum) * fabsf(sdf);
    }

    // block reduce (3 waves)
#pragma unroll
    for (int o = 32; o > 0; o >>= 1) acc += __shfl_down(acc, o, 64);
    __shared__ float wpart[3];
    int lane = tid & 63, wid = tid >> 6;
    if (lane == 0) wpart[wid] = acc;
    __syncthreads();
    if (tid == 0) {
        float v = wpart[0] + wpart[1] + wpart[2];
        atomicAdd(out, v * (1.0f / (float)(NB * NC * SPATIAL)));
    }
}

extern "C" void kernel_launch(void* const* d_in, const int* in_sizes, int n_in,
                              void* d_out, int out_size, void* d_ws, size_t ws_size,
                              hipStream_t stream) {
    const float* pred = (const float*)d_in[0];
    const int* target = (const int*)d_in[1];
    float* out = (float*)d_out;
    float* F = (float*)d_ws;   // 16 * 110592 floats = 7.08 MB

    edt_wh_kernel<<<2 * NB * NC * NLINE, 192, 0, stream>>>(target, F, out);   // 768 blocks
    edt_d_reduce_kernel<<<NB * NC * NLINE, 192, 0, stream>>>(pred, F, out);   // 384 blocks
}

// Round 3
// 94.381 us; speedup vs baseline: 1.3113x; 1.0776x over previous
//
#include <hip/hip_runtime.h>
#include <hip/hip_bf16.h>

// BoundaryLoss: out = mean(|softmax(pred,axis=1) * (posEDT - negEDT)|)
// B=2, C=4, D=H=W=48. Exact separable squared EDT.
// Min-plus reformulation: f[j] + (x0+k-j)^2 = (f[j]+dj^2) + 2k*dj + k^2,
// dj = x0-j. For fixed k all candidates share the +k^2 shift, so we min over
// fma(2k, dj, aj) and add k^2 once. All winning-chain values are exact
// integers < 2^14 in fp32 => bit-identical to the reference EDT.
//
// Kernel A (768 blocks): per (vol,d) slab: onehot -> min-plus w -> h -> F
// Kernel B (768 blocks): per (b,c,h,half): pos+neg slabs -> min-plus d ->
//   sdf + softmax + |.| -> block reduce -> atomicAdd

#define SPATIAL 110592   // 48^3
#define NB 2
#define NC 4
#define NLINE 48
#define SLABP 49         // padded LDS row stride

__global__ __launch_bounds__(192) void edt_wh_kernel(const int* __restrict__ target,
                                                     float* __restrict__ F,
                                                     float* __restrict__ out) {
    __shared__ float slab[NLINE * SLABP];
    int blk = blockIdx.x;                 // vol*48 + d ; vol = mask*8 + b*4 + c
    int vol = blk / NLINE, d = blk - vol * NLINE;
    int mask = vol >> 3;
    int b = (vol >> 2) & 1, c = vol & 3;
    int tid = threadIdx.x;
    if (blk == 0 && tid == 0) *out = 0.0f;   // visible to kernel B (stream order)

    const int* tslab = target + (b * NLINE + d) * (NLINE * NLINE);
    for (int idx = tid; idx < NLINE * NLINE; idx += 192) {
        int h = idx / NLINE, w = idx - h * NLINE;
        bool pos = (tslab[idx] == c);
        bool set = mask ? !pos : pos;
        slab[h * SLABP + w] = set ? 0.0f : 1e9f;
    }
    __syncthreads();

    // ---- transform along w: thread -> (row h = tid>>2, chunk (tid&3)*12)
    {
        int h = tid >> 2, cx = (tid & 3) * 12;
        float m[12];
#pragma unroll
        for (int k = 0; k < 12; ++k) m[k] = 1e30f;
        float dj = (float)cx;                      // x0 - j, iterated
        for (int j = 0; j < NLINE; ++j) {
            float fj = slab[h * SLABP + j];
            float aj = fmaf(dj, dj, fj);
#pragma unroll
            for (int k = 0; k < 12; ++k)
                m[k] = fminf(m[k], fmaf((float)(2 * k), dj, aj));
            dj -= 1.0f;
        }
        __syncthreads();
#pragma unroll
        for (int k = 0; k < 12; ++k)
            slab[h * SLABP + cx + k] = m[k] + (float)(k * k);
        __syncthreads();
    }

    // ---- transform along h: thread -> (column w = tid>>2, chunk over h)
    {
        int w = tid >> 2, cx = (tid & 3) * 12;
        float m[12];
#pragma unroll
        for (int k = 0; k < 12; ++k) m[k] = 1e30f;
        float dj = (float)cx;
        for (int j = 0; j < NLINE; ++j) {
            float fj = slab[j * SLABP + w];
            float aj = fmaf(dj, dj, fj);
#pragma unroll
            for (int k = 0; k < 12; ++k)
                m[k] = fminf(m[k], fmaf((float)(2 * k), dj, aj));
            dj -= 1.0f;
        }
        __syncthreads();
#pragma unroll
        for (int k = 0; k < 12; ++k)
            slab[(cx + k) * SLABP + w] = m[k] + (float)(k * k);
        __syncthreads();
    }

    float* fvol = F + (long)vol * SPATIAL + (long)d * (NLINE * NLINE);
    for (int idx = tid; idx < NLINE * NLINE; idx += 192) {
        int h = idx / NLINE, w = idx - h * NLINE;
        fvol[idx] = slab[h * SLABP + w];
    }
}

__global__ __launch_bounds__(192) void edt_d_reduce_kernel(const float* __restrict__ pred,
                                                           const float* __restrict__ F,
                                                           float* __restrict__ out) {
    __shared__ float slabP[NLINE * SLABP];
    __shared__ float slabN[NLINE * SLABP];
    int blk = blockIdx.x;                 // ((b*4+c)*48 + h)*2 + half
    int half = blk & 1;
    int rest = blk >> 1;
    int bc = rest / NLINE, h = rest - bc * NLINE;
    int b = bc >> 2, c = bc & 3;
    int tid = threadIdx.x;

    const float* fp = F + (long)bc * SPATIAL;
    const float* fn = F + (long)(8 + bc) * SPATIAL;
    for (int idx = tid; idx < NLINE * NLINE; idx += 192) {
        int dd = idx / NLINE, w = idx - dd * NLINE;
        long g = (long)dd * (NLINE * NLINE) + h * NLINE + w;
        slabP[dd * SLABP + w] = fp[g];
        slabN[dd * SLABP + w] = fn[g];
    }
    __syncthreads();

    // min-plus along d (both slabs): thread -> (w = tid>>2, 6-output chunk)
    int w = tid >> 2;
    int cx = half * 24 + (tid & 3) * 6;
    float mP[6], mN[6];
#pragma unroll
    for (int k = 0; k < 6; ++k) { mP[k] = 1e30f; mN[k] = 1e30f; }
    float dj = (float)cx;
    for (int j = 0; j < NLINE; ++j) {
        float fpj = slabP[j * SLABP + w];
        float fnj = slabN[j * SLABP + w];
        float aP = fmaf(dj, dj, fpj);
        float aN = fmaf(dj, dj, fnj);
#pragma unroll
        for (int k = 0; k < 6; ++k) {
            float tk = (float)(2 * k);
            mP[k] = fminf(mP[k], fmaf(tk, dj, aP));
            mN[k] = fminf(mN[k], fmaf(tk, dj, aN));
        }
        dj -= 1.0f;
    }

    // contribution: |softmax_c(pred) * sdf|
    float acc = 0.0f;
    long pbase = (long)b * NC * SPATIAL + (long)h * NLINE + w;
#pragma unroll
    for (int k = 0; k < 6; ++k) {
        int d = cx + k;
        float psq = mP[k] + (float)(k * k);
        float nsq = mN[k] + (float)(k * k);
        float sdf = (psq > 1e8f) ? 0.0f : (sqrtf(psq) - sqrtf(nsq));
        long base = pbase + (long)d * (NLINE * NLINE);
        float p0 = pred[base];
        float p1 = pred[base + SPATIAL];
        float p2 = pred[base + 2 * SPATIAL];
        float p3 = pred[base + 3 * SPATIAL];
        float mx = fmaxf(fmaxf(p0, p1), fmaxf(p2, p3));
        float e0 = __expf(p0 - mx), e1 = __expf(p1 - mx);
        float e2 = __expf(p2 - mx), e3 = __expf(p3 - mx);
        float sum = e0 + e1 + e2 + e3;
        float ec = (c == 0) ? e0 : (c == 1) ? e1 : (c == 2) ? e2 : e3;
        acc += (ec / sum) * fabsf(sdf);
    }

    // block reduce (3 waves)
#pragma unroll
    for (int o = 32; o > 0; o >>= 1) acc += __shfl_down(acc, o, 64);
    __shared__ float wpart[3];
    int lane = tid & 63, wid = tid >> 6;
    if (lane == 0) wpart[wid] = acc;
    __syncthreads();
    if (tid == 0) {
        float v = wpart[0] + wpart[1] + wpart[2];
        atomicAdd(out, v * (1.0f / (float)(NB * NC * SPATIAL)));
    }
}

extern "C" void kernel_launch(void* const* d_in, const int* in_sizes, int n_in,
                              void* d_out, int out_size, void* d_ws, size_t ws_size,
                              hipStream_t stream) {
    const float* pred = (const float*)d_in[0];
    const int* target = (const int*)d_in[1];
    float* out = (float*)d_out;
    float* F = (float*)d_ws;   // 16 * 110592 floats = 7.08 MB

    edt_wh_kernel<<<2 * NB * NC * NLINE, 192, 0, stream>>>(target, F, out);        // 768 blocks
    edt_d_reduce_kernel<<<2 * NB * NC * NLINE, 192, 0, stream>>>(pred, F, out);    // 768 blocks
}

// Round 5
// 91.156 us; speedup vs baseline: 1.3577x; 1.0354x over previous
//
#include <hip/hip_runtime.h>
#include <hip/hip_bf16.h>

// BoundaryLoss: out = mean(|softmax(pred,axis=1) * (posEDT - negEDT)|)
// B=2, C=4, D=H=W=48. Exact separable squared EDT, bit-matching the JAX ref.
//
// Two kernels (cooperative launch does NOT work in this harness - R4 failed
// with a silent no-run; keep plain stream-ordered launches):
//  A (768 blocks): per (vol,d) slab: onehot -> pass1 along w (binary two-sweep
//    L1 scan + square; exact) -> pass2 along h (min-plus, min3-folded) -> F.
//  B (768 blocks): per (b,c,h,half): pos+neg (d,w) slabs -> min-plus along d
//    (min3-folded) -> sdf + softmax + |.| -> block reduce -> atomicAdd.
//
// Min-plus algebra: f[j] + (x0+k-j)^2 = (f[j]+dj^2) + 2k*dj + k^2, dj=x0-j.
// All winning-chain values are exact integers < 2^14 in fp32 => bit-exact.
// min3 fold: fminf(fminf(m,c0),c1) -> v_min3_f32 (exact, order-free).

#define SPATIAL 110592   // 48^3
#define NB 2
#define NC 4
#define NLINE 48
#define SLABP 49         // padded LDS row stride

__global__ __launch_bounds__(192) void edt_wh_kernel(const int* __restrict__ target,
                                                     float* __restrict__ F,
                                                     float* __restrict__ out) {
    __shared__ float slab[NLINE * SLABP];
    __shared__ int tsh[NLINE * NLINE];
    int blk = blockIdx.x;                 // vol*48 + d ; vol = mask*8 + b*4 + c
    int vol = blk / NLINE, d = blk - vol * NLINE;
    int mask = vol >> 3;
    int b = (vol >> 2) & 1, c = vol & 3;
    int tid = threadIdx.x;
    if (blk == 0 && tid == 0) *out = 0.0f;   // visible to kernel B (stream order)

    // stage target slab into LDS (coalesced)
    const int* tslab = target + (b * NLINE + d) * (NLINE * NLINE);
    for (int idx = tid; idx < NLINE * NLINE; idx += 192) tsh[idx] = tslab[idx];
    __syncthreads();

    // ---- pass 1 along w: binary two-sweep L1 scan (thread = row h)
    if (tid < NLINE) {
        int h = tid;
        int n = 64;
        for (int w = 0; w < NLINE; ++w) {
            int t = tsh[h * NLINE + w];
            bool set = mask ? (t != c) : (t == c);
            n = set ? 0 : n + 1;
            slab[h * SLABP + w] = (float)n;
        }
        n = 64;
        for (int w = NLINE - 1; w >= 0; --w) {
            int t = tsh[h * NLINE + w];
            bool set = mask ? (t != c) : (t == c);
            n = set ? 0 : n + 1;
            float m = fminf(slab[h * SLABP + w], (float)n);
            slab[h * SLABP + w] = (m >= 48.0f) ? 1e9f : m * m;
        }
    }
    __syncthreads();

    // ---- pass 2 along h: thread -> (column w = tid>>2, 12-chunk over h)
    {
        int w = tid >> 2, cx = (tid & 3) * 12;
        float m[12];
#pragma unroll
        for (int k = 0; k < 12; ++k) m[k] = 1e30f;
        float dj = (float)cx;
        for (int j = 0; j < NLINE; j += 2) {
            float f0 = slab[j * SLABP + w];
            float f1 = slab[(j + 1) * SLABP + w];
            float a0 = fmaf(dj, dj, f0);
            float dj1 = dj - 1.0f;
            float a1 = fmaf(dj1, dj1, f1);
#pragma unroll
            for (int k = 0; k < 12; ++k) {
                float tk = (float)(2 * k);
                m[k] = fminf(fminf(m[k], fmaf(tk, dj, a0)), fmaf(tk, dj1, a1));
            }
            dj -= 2.0f;
        }
        __syncthreads();               // all reads done before in-place writes
#pragma unroll
        for (int k = 0; k < 12; ++k)
            slab[(cx + k) * SLABP + w] = m[k] + (float)(k * k);
        __syncthreads();
    }

    // store slab -> F[vol][d][h][w] (coalesced)
    float* fvol = F + (long)vol * SPATIAL + (long)d * (NLINE * NLINE);
    for (int idx = tid; idx < NLINE * NLINE; idx += 192) {
        int h = idx / NLINE, ww = idx - h * NLINE;
        fvol[idx] = slab[h * SLABP + ww];
    }
}

__global__ __launch_bounds__(192) void edt_d_reduce_kernel(const float* __restrict__ pred,
                                                           const float* __restrict__ F,
                                                           float* __restrict__ out) {
    __shared__ float slabP[NLINE * SLABP];
    __shared__ float slabN[NLINE * SLABP];
    int blk = blockIdx.x;                 // ((b*4+c)*48 + h)*2 + half
    int half = blk & 1;
    int rest = blk >> 1;
    int bc = rest / NLINE, h = rest - bc * NLINE;
    int b = bc >> 2, c = bc & 3;
    int tid = threadIdx.x;

    const float* fp = F + (long)bc * SPATIAL;
    const float* fn = F + (long)(8 + bc) * SPATIAL;
    for (int idx = tid; idx < NLINE * NLINE; idx += 192) {
        int dd = idx / NLINE, ww = idx - dd * NLINE;
        long g = (long)dd * (NLINE * NLINE) + h * NLINE + ww;
        slabP[dd * SLABP + ww] = fp[g];
        slabN[dd * SLABP + ww] = fn[g];
    }
    __syncthreads();

    // min-plus along d (both slabs): thread -> (w = tid>>2, 6-chunk)
    int w = tid >> 2;
    int cx = half * 24 + (tid & 3) * 6;
    float mP[6], mN[6];
#pragma unroll
    for (int k = 0; k < 6; ++k) { mP[k] = 1e30f; mN[k] = 1e30f; }
    float dj = (float)cx;
    for (int j = 0; j < NLINE; j += 2) {
        float fp0 = slabP[j * SLABP + w];
        float fn0 = slabN[j * SLABP + w];
        float fp1 = slabP[(j + 1) * SLABP + w];
        float fn1 = slabN[(j + 1) * SLABP + w];
        float dj1 = dj - 1.0f;
        float aP0 = fmaf(dj, dj, fp0),  aP1 = fmaf(dj1, dj1, fp1);
        float aN0 = fmaf(dj, dj, fn0),  aN1 = fmaf(dj1, dj1, fn1);
#pragma unroll
        for (int k = 0; k < 6; ++k) {
            float tk = (float)(2 * k);
            mP[k] = fminf(fminf(mP[k], fmaf(tk, dj, aP0)), fmaf(tk, dj1, aP1));
            mN[k] = fminf(fminf(mN[k], fmaf(tk, dj, aN0)), fmaf(tk, dj1, aN1));
        }
        dj -= 2.0f;
    }

    // contribution: |softmax_c(pred) * sdf|
    float acc = 0.0f;
    long pbase = (long)b * NC * SPATIAL + (long)h * NLINE + w;
#pragma unroll
    for (int k = 0; k < 6; ++k) {
        int d = cx + k;
        float psq = mP[k] + (float)(k * k);
        float nsq = mN[k] + (float)(k * k);
        float sdf = (psq > 1e8f) ? 0.0f : (sqrtf(psq) - sqrtf(nsq));
        long base = pbase + (long)d * (NLINE * NLINE);
        float p0 = pred[base];
        float p1 = pred[base + SPATIAL];
        float p2 = pred[base + 2 * SPATIAL];
        float p3 = pred[base + 3 * SPATIAL];
        float mx = fmaxf(fmaxf(p0, p1), fmaxf(p2, p3));
        float e0 = __expf(p0 - mx), e1 = __expf(p1 - mx);
        float e2 = __expf(p2 - mx), e3 = __expf(p3 - mx);
        float sum = e0 + e1 + e2 + e3;
        float ec = (c == 0) ? e0 : (c == 1) ? e1 : (c == 2) ? e2 : e3;
        acc += (ec / sum) * fabsf(sdf);
    }

    // block reduce (3 waves)
#pragma unroll
    for (int o = 32; o > 0; o >>= 1) acc += __shfl_down(acc, o, 64);
    __shared__ float wpart[3];
    int lane = tid & 63, wid = tid >> 6;
    if (lane == 0) wpart[wid] = acc;
    __syncthreads();
    if (tid == 0) {
        float v = wpart[0] + wpart[1] + wpart[2];
        atomicAdd(out, v * (1.0f / (float)(NB * NC * SPATIAL)));
    }
}

extern "C" void kernel_launch(void* const* d_in, const int* in_sizes, int n_in,
                              void* d_out, int out_size, void* d_ws, size_t ws_size,
                              hipStream_t stream) {
    const float* pred = (const float*)d_in[0];
    const int* target = (const int*)d_in[1];
    float* out = (float*)d_out;
    float* F = (float*)d_ws;   // 16 * 110592 floats = 7.08 MB

    edt_wh_kernel<<<2 * NB * NC * NLINE, 192, 0, stream>>>(target, F, out);        // 768 blocks
    edt_d_reduce_kernel<<<2 * NB * NC * NLINE, 192, 0, stream>>>(pred, F, out);    // 768 blocks
}